// Round 20
// baseline (1081.031 us; speedup 1.0000x reference)
//
#include <hip/hip_runtime.h>

typedef unsigned short u16;
typedef unsigned int u32;
typedef __attribute__((ext_vector_type(8))) short v8s;
typedef __attribute__((ext_vector_type(4))) float f32x4;

#define RPB 64             // rows per block (4 waves x 16 rows)
#define THREADS 256
#define NSB 512            // sort blocks
// u16 offsets inside Wf
#define W1F 0
#define W2F 8192
#define W3F 73728
#define W4F 139264
#define TOTW 143360
// workspace byte offsets
#define BH_OFF 286720
#define PERM_OFF 305152

#define MFMA(w, b, c) __builtin_amdgcn_mfma_f32_16x16x32_bf16((w), (b), (c), 0, 0, 0)

typedef __attribute__((address_space(1))) const unsigned int gu32;
typedef __attribute__((address_space(3))) unsigned int su32;
__device__ __forceinline__ void gld16(const u16* g, u16* l) {
  __builtin_amdgcn_global_load_lds((gu32*)g, (su32*)l, 16, 0, 0);
}

__device__ __forceinline__ u32 pk2(float a, float b) {
  u32 r;
  asm("v_cvt_pk_bf16_f32 %0, %1, %2" : "=v"(r) : "v"(a), "v"(b));
  return r;
}
__device__ __forceinline__ float bfu(u32 w, int hi) {
  return __uint_as_float(hi ? (w & 0xffff0000u) : (w << 16));
}
__device__ __forceinline__ f32x4 silu4(f32x4 v) {
  f32x4 r;
#pragma unroll
  for (int i = 0; i < 4; ++i) r[i] = v[i] * __builtin_amdgcn_rcpf(1.0f + __expf(-v[i]));
  return r;
}

// ---------------------------------------------------------------------------
// Weight prep (round-16-proven): bf16, A-fragment order, k-slot permutation
// slot(q,j) <-> feature f = 32ks+16*(j>>2)+4q+(j&3).
// W1: K 12->32; f6..11 dup hi/lo; f12 = b1 (const-1 input folds layer-1 bias).
// W4: out-features padded 4->16. W2/W3 slice-major: (ks*16+mt)*512.
// ---------------------------------------------------------------------------
__global__ void prep_weights(const float* __restrict__ W1, const float* __restrict__ b1,
                             const float* __restrict__ W2, const float* __restrict__ W3,
                             const float* __restrict__ W4, u16* __restrict__ Wf) {
  int e = blockIdx.x * 256 + threadIdx.x;
  if (e >= TOTW) return;
  float val = 0.0f;
  if (e < W2F) {
    int mt = e >> 9, idx = e & 511, l = idx >> 3, j = idx & 7;
    int q = l >> 4, m = l & 15;
    int f = 16 * (j >> 2) + 4 * q + (j & 3);
    int col = mt * 16 + m;
    val = (f < 6) ? W1[f * 256 + col]
        : ((f < 12) ? W1[(f - 6) * 256 + col]
        : ((f == 12) ? b1[col] : 0.0f));
  } else if (e < W3F) {
    int e2 = e - W2F, blk = e2 >> 9, idx = e2 & 511, l = idx >> 3, j = idx & 7;
    int ks = blk >> 4, mt = blk & 15, q = l >> 4, m = l & 15;
    int f = 32 * ks + 16 * (j >> 2) + 4 * q + (j & 3);
    val = W2[f * 256 + mt * 16 + m];
  } else if (e < W4F) {
    int e2 = e - W3F, blk = e2 >> 9, idx = e2 & 511, l = idx >> 3, j = idx & 7;
    int ks = blk >> 4, mt = blk & 15, q = l >> 4, m = l & 15;
    int f = 32 * ks + 16 * (j >> 2) + 4 * q + (j & 3);
    val = W3[f * 256 + mt * 16 + m];
  } else {
    int e2 = e - W4F, ks = e2 >> 9, idx = e2 & 511, l = idx >> 3, j = idx & 7;
    int q = l >> 4, m = l & 15;
    int f = 32 * ks + 16 * (j >> 2) + 4 * q + (j & 3);
    val = (m < 4) ? W4[f * 4 + m] : 0.0f;
  }
  Wf[e] = (u16)pk2(val, val);
}

// ------------------ counting sort by n_full (LDS-local) ---------------------
__global__ void hist_blocks(const float* __restrict__ zf, int* __restrict__ bh, int B) {
  __shared__ int h[9];
  int t = threadIdx.x;
  if (t < 9) h[t] = 0;
  __syncthreads();
  int r = blockIdx.x * 512 + t;
  if (r < B) {
    int nf = min(max((int)floorf(zf[r] * 8.0f), 0), 8);
    atomicAdd(&h[nf], 1);
  }
  __syncthreads();
  if (t < 9) bh[blockIdx.x * 9 + t] = h[t];
}

__global__ void scan_offsets(int* __restrict__ bh) {
  __shared__ int S[NSB * 9];
  __shared__ int tot[9], ebase[9];
  int t = threadIdx.x;
  for (int i = t; i < NSB * 9; i += 512) S[i] = bh[i];
  __syncthreads();
  if (t < 9) {
    int s = 0;
    for (int b = 0; b < NSB; ++b) s += S[b * 9 + t];
    tot[t] = s;
  }
  __syncthreads();
  if (t == 0) {
    int s = 0;
    for (int i = 0; i < 9; ++i) { ebase[i] = s; s += tot[i]; }
  }
  __syncthreads();
  if (t < 9) {
    int off = ebase[t];
    for (int b = 0; b < NSB; ++b) { int c = S[b * 9 + t]; S[b * 9 + t] = off; off += c; }
  }
  __syncthreads();
  for (int i = t; i < NSB * 9; i += 512) bh[i] = S[i];
}

__global__ void scatter_sorted(const float* __restrict__ zf, const int* __restrict__ bh,
                               int* __restrict__ perm, int B) {
  __shared__ int off[9];
  int t = threadIdx.x;
  if (t < 9) off[t] = bh[blockIdx.x * 9 + t];
  __syncthreads();
  int r = blockIdx.x * 512 + t;
  if (r < B) {
    int nf = min(max((int)floorf(zf[r] * 8.0f), 0), 8);
    int pos = atomicAdd(&off[nf], 1);
    perm[pos] = r;
  }
}

// ---------------------------------------------------------------------------
// Main kernel: round-16 structure (4 waves x 16 rows, acc[16] in 64 AGPRs)
// with each 16-fragment k-slice SPLIT: frags 0..11 via the LDS ring (3 x
// 12KB slots), frags 12..15 read directly from global (L2-resident) into a
// double-buffered register set one phase ahead. LDS reads/wave-eval
// 280 -> 216 (the measured wall); the 4 reg-frags ride the idle vector-mem
// pipe. 7 vmem ops issued per phase (3 gld16 + 4 reg loads) -> counted
// vmcnt(7). waves_per_eu(1,2): no arch cap (live ~165 arch + 64 AGPR = 229
// <= 256 -> 2 waves/EU, no spill). MFMA order 0..15 unchanged -> numerics
// identical to round 16 (absmax 0.015625).
// ---------------------------------------------------------------------------
__global__ __attribute__((amdgpu_flat_work_group_size(256, 256)))
__attribute__((amdgpu_waves_per_eu(1, 2))) void pinn_main(
    const float* __restrict__ sdz, const float* __restrict__ zf,
    const u16* __restrict__ Wf, const int* __restrict__ perm,
    const float* __restrict__ b2, const float* __restrict__ b3,
    const float* __restrict__ b4, float* __restrict__ out) {
  __shared__ __align__(16) u16 ringS[3][6144];   // 36 KB: 3 x 12KB (12 frags)
  __shared__ __align__(16) u16 W1s[8192];        // 16 KB
  __shared__ __align__(16) u16 W4s[4096];        // 8 KB
  __shared__ __align__(16) float biasS[528];     // b2|b3|b4-padded
  __shared__ __align__(16) float stS[RPB * 4];
  __shared__ float qopS[RPB], dzS[RPB], fracS[RPB];
  __shared__ int nfS[RPB], rowG[RPB];

  const int t = threadIdx.x;
  const int lane = t & 63;
  const int q = lane >> 4;    // k-slot group / D row-block
  const int n = lane & 15;    // batch column within tile
  const int wv = t >> 6;      // 0..3
  const int rb = wv * 16;     // wave's first block-local row

  if (t < RPB) {
    int rg = perm[blockIdx.x * RPB + t];
    rowG[t] = rg;
    const float* p = sdz + (size_t)rg * 6;
    stS[t * 4 + 0] = p[0]; stS[t * 4 + 1] = p[1];
    stS[t * 4 + 2] = p[2]; stS[t * 4 + 3] = p[3];
    qopS[t] = p[4];
    dzS[t] = p[5] * 0.125f;
    float cs = zf[rg] * 8.0f;
    float nfl = floorf(cs);
    nfS[t] = (int)nfl;
    fracS[t] = cs - nfl;
  }
  biasS[t] = b2[t]; biasS[256 + t] = b3[t];
  if (t < 16) biasS[512 + t] = (t < 4) ? b4[t] : 0.0f;
  // stage W1 (16 chunks: 4 waves x 4) and W4 (8 chunks: 4 waves x 2)
#pragma unroll
  for (int c = 0; c < 4; ++c)
    gld16(Wf + W1F + (c * 4 + wv) * 512 + lane * 8, &W1s[(c * 4 + wv) * 512]);
#pragma unroll
  for (int c = 0; c < 2; ++c)
    gld16(Wf + W4F + (c * 4 + wv) * 512 + lane * 8, &W4s[(c * 4 + wv) * 512]);

  f32x4 acc[16];
  v8s bact[8];
  v8s wreg[2][4];             // reg-frag double buffer (parity = phase&1)
  const f32x4 Z4 = {0.0f, 0.0f, 0.0f, 0.0f};

  // prologue: slice 0 (12 LDS frags into slot 0 + 4 reg frags, parity 0)
  {
    u16* dst_ = &ringS[0][0];
#pragma unroll
    for (int c_ = 0; c_ < 3; ++c_)
      gld16(Wf + W2F + (c_ * 4 + wv) * 512 + lane * 8, dst_ + (c_ * 4 + wv) * 512);
    const v8s* gsrc = (const v8s*)(Wf + W2F);
#pragma unroll
    for (int j = 0; j < 4; ++j) wreg[0][j] = gsrc[(12 + j) * 64 + lane];
  }
  __syncthreads();
  const int maxnf = nfS[RPB - 1];   // rows sorted by n_full
  int bc = 0;

#define PACK_BACT()                                              \
  do {                                                           \
    _Pragma("unroll") for (int ks = 0; ks < 8; ++ks) {           \
      f32x4 a0 = silu4(acc[2 * ks]);                             \
      f32x4 a1 = silu4(acc[2 * ks + 1]);                         \
      union { int4 i; v8s s; } u_;                               \
      u_.i.x = (int)pk2(a0[0], a0[1]);                           \
      u_.i.y = (int)pk2(a0[2], a0[3]);                           \
      u_.i.z = (int)pk2(a1[0], a1[1]);                           \
      u_.i.w = (int)pk2(a1[2], a1[3]);                           \
      bact[ks] = u_.s;                                           \
    }                                                            \
  } while (0)

  for (int ev = 0; ev <= maxnf; ++ev) {
    const bool partial = (ev == maxnf);

    // ---- layer-1 B-fragment: hi/lo split + const-1 slot (f=12, q=3) ----
    v8s b1f;
    {
      const int row = rb + n;
      const float4 st = *(const float4*)&stS[row * 4];
      const float qop = qopS[row];
      const float dzv = partial ? fracS[row] * dzS[row] : dzS[row];
      u32 h01 = pk2(st.x, st.y), h23 = pk2(st.z, st.w), hqd = pk2(qop, dzv);
      float l0 = st.x - bfu(h01, 0), l1 = st.y - bfu(h01, 1);
      float l2 = st.z - bfu(h23, 0), l3 = st.w - bfu(h23, 1);
      float lq = qop - bfu(hqd, 0), ld = dzv - bfu(hqd, 1);
      u32 w0 = 0, w1 = 0;
      if (q == 0) { w0 = h01; w1 = h23; }
      else if (q == 1) { w0 = hqd; w1 = pk2(l0, l1); }
      else if (q == 2) { w0 = pk2(l2, l3); w1 = pk2(lq, ld); }
      else { w0 = 0x00003F80u; }   // f=12 slot = 1.0 -> W1 row 12 = b1
      union { int4 i; v8s s; } u_;
      u_.i.x = (int)w0; u_.i.y = (int)w1; u_.i.z = 0; u_.i.w = 0;
      b1f = u_.s;
    }

    // ---- L1: acc = W1^T @ [x,1] (bias via const-1 feature) ----
#pragma unroll
    for (int mt = 0; mt < 16; ++mt) {
      const v8s w = *(const v8s*)&W1s[mt * 512 + lane * 8];
      acc[mt] = MFMA(w, b1f, Z4);
      if ((mt & 3) == 3) __builtin_amdgcn_sched_barrier(0);
    }
    PACK_BACT();

    // ---- L2, L3: per phase = 12 LDS frags + 4 reg frags; vmcnt(7) ----
#pragma unroll
    for (int layer = 0; layer < 2; ++layer) {
      const int Lb = (layer == 0) ? 0 : 256;
#pragma unroll
      for (int mt = 0; mt < 16; ++mt) {
        const float4 bb = *(const float4*)&biasS[Lb + mt * 16 + q * 4];
        const f32x4 binit = {bb.x, bb.y, bb.z, bb.w};
        acc[mt] = binit;
      }
#pragma unroll
      for (int ks = 0; ks < 8; ++ks) {
        const int pc = ((layer << 3) + ks) & 1;     // this phase's parity
        int bn = bc + 1; if (bn == 3) bn = 0;
        {
          // issue next slice: 3 gld16 (frags 0..11) + 4 reg loads (12..15)
          const int sp = ((layer << 3) + ks + 1) & 15;
          const int noff = ((sp >> 3) ? W3F : W2F) + (sp & 7) * 8192;
          u16* dst_ = &ringS[bn][0];
#pragma unroll
          for (int c_ = 0; c_ < 3; ++c_)
            gld16(Wf + noff + (c_ * 4 + wv) * 512 + lane * 8,
                  dst_ + (c_ * 4 + wv) * 512);
          const v8s* gsrc = (const v8s*)(Wf + noff);
          if (pc == 0) {
#pragma unroll
            for (int j = 0; j < 4; ++j) wreg[1][j] = gsrc[(12 + j) * 64 + lane];
          } else {
#pragma unroll
            for (int j = 0; j < 4; ++j) wreg[0][j] = gsrc[(12 + j) * 64 + lane];
          }
        }
        asm volatile("s_waitcnt vmcnt(7)" ::: "memory");  // own phase's 7 done
        __builtin_amdgcn_sched_barrier(0);
        __builtin_amdgcn_s_barrier();            // publish; NO vmcnt(0) drain
        __builtin_amdgcn_sched_barrier(0);
        asm volatile("" ::: "memory");
        const u16* buf = &ringS[bc][0];
        __builtin_amdgcn_s_setprio(1);
#pragma unroll
        for (int grp = 0; grp < 3; ++grp) {
#pragma unroll
          for (int i2 = 0; i2 < 4; ++i2) {
            const int i = grp * 4 + i2;
            const v8s w = *(const v8s*)&buf[i * 512 + lane * 8];
            acc[i] = MFMA(w, bact[ks], acc[i]);
          }
          __builtin_amdgcn_sched_barrier(0);     // cap w-temps at 4 frags
        }
        if (pc == 0) {
#pragma unroll
          for (int j = 0; j < 4; ++j)
            acc[12 + j] = MFMA(wreg[0][j], bact[ks], acc[12 + j]);
        } else {
#pragma unroll
          for (int j = 0; j < 4; ++j)
            acc[12 + j] = MFMA(wreg[1][j], bact[ks], acc[12 + j]);
        }
        __builtin_amdgcn_s_setprio(0);
        bc = bn;
      }
      PACK_BACT();
    }

    // ---- L4 + masked state update (stS rows are wave-private) ----
    {
      const float4 bb = *(const float4*)&biasS[512 + q * 4];
      f32x4 a4 = {bb.x, bb.y, bb.z, bb.w};
#pragma unroll
      for (int ks = 0; ks < 8; ++ks) {
        const v8s w = *(const v8s*)&W4s[ks * 512 + lane * 8];
        a4 = MFMA(w, bact[ks], a4);
        if ((ks & 3) == 3) __builtin_amdgcn_sched_barrier(0);
      }
      if (q == 0) {
        const int row = rb + n;
        const bool act = partial ? (fracS[row] > 1e-6f) : (nfS[row] > ev);
        if (act) {
          float4 cur = *(float4*)&stS[row * 4];
          cur.x += a4[0]; cur.y += a4[1];
          cur.z += a4[2]; cur.w += a4[3];
          *(float4*)&stS[row * 4] = cur;
        }
      }
    }
  }
  __syncthreads();   // drains remaining ring prefetch + stS visibility

  // scattered output write (16B per row, rows permuted)
  {
    const int i = t;   // RPB*4 == THREADS
    out[(size_t)rowG[i >> 2] * 4 + (i & 3)] = stS[i];
  }
}

extern "C" void kernel_launch(void* const* d_in, const int* in_sizes, int n_in,
                              void* d_out, int out_size, void* d_ws, size_t ws_size,
                              hipStream_t stream) {
  const float* sdz = (const float*)d_in[0];
  const float* zfr = (const float*)d_in[1];
  const float* W1 = (const float*)d_in[2];
  const float* b1 = (const float*)d_in[3];
  const float* W2 = (const float*)d_in[4];
  const float* b2 = (const float*)d_in[5];
  const float* W3 = (const float*)d_in[6];
  const float* b3 = (const float*)d_in[7];
  const float* W4 = (const float*)d_in[8];
  const float* b4 = (const float*)d_in[9];

  char* ws = (char*)d_ws;
  u16* Wf = (u16*)ws;
  int* bh = (int*)(ws + BH_OFF);
  int* perm = (int*)(ws + PERM_OFF);

  const int B = in_sizes[1];   // 262144

  prep_weights<<<(TOTW + 255) / 256, 256, 0, stream>>>(W1, b1, W2, W3, W4, Wf);
  hist_blocks<<<NSB, 512, 0, stream>>>(zfr, bh, B);
  scan_offsets<<<1, 512, 0, stream>>>(bh);
  scatter_sorted<<<NSB, 512, 0, stream>>>(zfr, bh, perm, B);
  pinn_main<<<B / RPB, THREADS, 0, stream>>>(sdz, zfr, Wf, perm, b2, b3, b4,
                                             (float*)d_out);
}

// Round 21
// 526.119 us; speedup vs baseline: 2.0547x; 2.0547x over previous
//
#include <hip/hip_runtime.h>

typedef unsigned short u16;
typedef unsigned int u32;
typedef __attribute__((ext_vector_type(8))) short v8s;
typedef __attribute__((ext_vector_type(4))) float f32x4;

#define RPB 64             // rows per block (4 waves x 16 rows)
#define THREADS 256
#define NSB 512            // sort blocks (512 x 512 threads = 262144)
// u16 offsets inside Wf
#define W1F 0
#define W2F 8192
#define W3F 73728
#define W4F 139264
#define TOTW 143360
// workspace byte offsets
#define BH_OFF 286720      // blockHist: NSB*9*4 = 18432 B
#define PERM_OFF 305152    // perm: B*4

#define MFMA(w, b, c) __builtin_amdgcn_mfma_f32_16x16x32_bf16((w), (b), (c), 0, 0, 0)

typedef __attribute__((address_space(1))) const unsigned int gu32;
typedef __attribute__((address_space(3))) unsigned int su32;
__device__ __forceinline__ void gld16(const u16* g, u16* l) {
  __builtin_amdgcn_global_load_lds((gu32*)g, (su32*)l, 16, 0, 0);
}

__device__ __forceinline__ u32 pk2(float a, float b) {
  u32 r;
  asm("v_cvt_pk_bf16_f32 %0, %1, %2" : "=v"(r) : "v"(a), "v"(b));
  return r;
}
__device__ __forceinline__ float bfu(u32 w, int hi) {   // bf16 half -> f32
  return __uint_as_float(hi ? (w & 0xffff0000u) : (w << 16));
}
__device__ __forceinline__ f32x4 silu4(f32x4 v) {
  f32x4 r;
#pragma unroll
  for (int i = 0; i < 4; ++i) r[i] = v[i] * __builtin_amdgcn_rcpf(1.0f + __expf(-v[i]));
  return r;
}

// ---------------------------------------------------------------------------
// Weight prep: bf16, A-fragment order (lane l holds A[m=l&15][k-slot q*8+j]),
// k-slot permutation  slot(q,j) <-> feature f = 32ks+16*(j>>2)+4q+(j&3).
// W1: K padded 12->32; rows 6..11 duplicate 0..5 (hi/lo input split);
//     row 12 = b1 (constant-1 input feature folds the layer-1 bias in).
// W4: out-features padded 4->16. W2/W3 stored slice-major: (ks*16+mt)*512.
// ---------------------------------------------------------------------------
__global__ void prep_weights(const float* __restrict__ W1, const float* __restrict__ b1,
                             const float* __restrict__ W2, const float* __restrict__ W3,
                             const float* __restrict__ W4, u16* __restrict__ Wf) {
  int e = blockIdx.x * 256 + threadIdx.x;
  if (e >= TOTW) return;
  float val = 0.0f;
  if (e < W2F) {
    int mt = e >> 9, idx = e & 511, l = idx >> 3, j = idx & 7;
    int q = l >> 4, m = l & 15;
    int f = 16 * (j >> 2) + 4 * q + (j & 3);
    int col = mt * 16 + m;
    val = (f < 6) ? W1[f * 256 + col]
        : ((f < 12) ? W1[(f - 6) * 256 + col]
        : ((f == 12) ? b1[col] : 0.0f));
  } else if (e < W3F) {
    int e2 = e - W2F, blk = e2 >> 9, idx = e2 & 511, l = idx >> 3, j = idx & 7;
    int ks = blk >> 4, mt = blk & 15, q = l >> 4, m = l & 15;
    int f = 32 * ks + 16 * (j >> 2) + 4 * q + (j & 3);
    val = W2[f * 256 + mt * 16 + m];
  } else if (e < W4F) {
    int e2 = e - W3F, blk = e2 >> 9, idx = e2 & 511, l = idx >> 3, j = idx & 7;
    int ks = blk >> 4, mt = blk & 15, q = l >> 4, m = l & 15;
    int f = 32 * ks + 16 * (j >> 2) + 4 * q + (j & 3);
    val = W3[f * 256 + mt * 16 + m];
  } else {
    int e2 = e - W4F, ks = e2 >> 9, idx = e2 & 511, l = idx >> 3, j = idx & 7;
    int q = l >> 4, m = l & 15;
    int f = 32 * ks + 16 * (j >> 2) + 4 * q + (j & 3);
    val = (m < 4) ? W4[f * 4 + m] : 0.0f;
  }
  Wf[e] = (u16)pk2(val, val);
}

// ------------------ counting sort by n_full (LDS-local) ---------------------
__global__ void hist_blocks(const float* __restrict__ zf, int* __restrict__ bh, int B) {
  __shared__ int h[9];
  int t = threadIdx.x;
  if (t < 9) h[t] = 0;
  __syncthreads();
  int r = blockIdx.x * 512 + t;
  if (r < B) {
    int nf = min(max((int)floorf(zf[r] * 8.0f), 0), 8);
    atomicAdd(&h[nf], 1);
  }
  __syncthreads();
  if (t < 9) bh[blockIdx.x * 9 + t] = h[t];
}

__global__ void scan_offsets(int* __restrict__ bh) {
  __shared__ int S[NSB * 9];
  __shared__ int tot[9], ebase[9];
  int t = threadIdx.x;
  for (int i = t; i < NSB * 9; i += 512) S[i] = bh[i];
  __syncthreads();
  if (t < 9) {
    int s = 0;
    for (int b = 0; b < NSB; ++b) s += S[b * 9 + t];
    tot[t] = s;
  }
  __syncthreads();
  if (t == 0) {
    int s = 0;
    for (int i = 0; i < 9; ++i) { ebase[i] = s; s += tot[i]; }
  }
  __syncthreads();
  if (t < 9) {
    int off = ebase[t];
    for (int b = 0; b < NSB; ++b) { int c = S[b * 9 + t]; S[b * 9 + t] = off; off += c; }
  }
  __syncthreads();
  for (int i = t; i < NSB * 9; i += 512) bh[i] = S[i];
}

__global__ void scatter_sorted(const float* __restrict__ zf, const int* __restrict__ bh,
                               int* __restrict__ perm, int B) {
  __shared__ int off[9];
  int t = threadIdx.x;
  if (t < 9) off[t] = bh[blockIdx.x * 9 + t];
  __syncthreads();
  int r = blockIdx.x * 512 + t;
  if (r < B) {
    int nf = min(max((int)floorf(zf[r] * 8.0f), 0), 8);
    int pos = atomicAdd(&off[nf], 1);
    perm[pos] = r;
  }
}

// ---------------------------------------------------------------------------
// Main kernel (round-16 champion, restored): 4 waves x 16 rows; acc[16] in
// 64 AGPRs + ~126 arch VGPRs = 190/wave -> 2 waves/EU, no spill
// (waves_per_eu(2,2): arch cap 128). One full 16KB k-slice per barrier
// (16 ds_read + 16 MFMA), 16 barriers/eval. Ring = 3 x 16KB, issue-ahead-1,
// counted vmcnt(4) (never 0 in the loop). W1/W4 LDS-resident; b1 folded
// into W1 via const-1 input feature. Verified: 527us total, FETCH 16.5MB,
// WRITE 7.9MB, zero bank conflicts, absmax 0.015625.
// Falsified alternatives (rounds 17-20): 32x32 (spill), nt=2 (1 wave/EU),
// W1/W4 streaming + (2,3) (no occupancy gain), L2 reg-frags (1 wave/EU).
// ---------------------------------------------------------------------------
__global__ __attribute__((amdgpu_flat_work_group_size(256, 256)))
__attribute__((amdgpu_waves_per_eu(2, 2))) void pinn_main(
    const float* __restrict__ sdz, const float* __restrict__ zf,
    const u16* __restrict__ Wf, const int* __restrict__ perm,
    const float* __restrict__ b2, const float* __restrict__ b3,
    const float* __restrict__ b4, float* __restrict__ out) {
  __shared__ __align__(16) u16 ringS[3][8192];   // 48 KB: 3 x 16KB k-slices
  __shared__ __align__(16) u16 W1s[8192];        // 16 KB
  __shared__ __align__(16) u16 W4s[4096];        // 8 KB
  __shared__ __align__(16) float biasS[528];     // b2|b3|b4-padded
  __shared__ __align__(16) float stS[RPB * 4];
  __shared__ float qopS[RPB], dzS[RPB], fracS[RPB];
  __shared__ int nfS[RPB], rowG[RPB];

  const int t = threadIdx.x;
  const int lane = t & 63;
  const int q = lane >> 4;    // k-slot group / D row-block
  const int n = lane & 15;    // batch column within tile
  const int wv = t >> 6;      // 0..3
  const int rb = wv * 16;     // wave's first block-local row

  if (t < RPB) {
    int rg = perm[blockIdx.x * RPB + t];
    rowG[t] = rg;
    const float* p = sdz + (size_t)rg * 6;
    stS[t * 4 + 0] = p[0]; stS[t * 4 + 1] = p[1];
    stS[t * 4 + 2] = p[2]; stS[t * 4 + 3] = p[3];
    qopS[t] = p[4];
    dzS[t] = p[5] * 0.125f;
    float cs = zf[rg] * 8.0f;
    float nfl = floorf(cs);
    nfS[t] = (int)nfl;
    fracS[t] = cs - nfl;
  }
  biasS[t] = b2[t]; biasS[256 + t] = b3[t];
  if (t < 16) biasS[512 + t] = (t < 4) ? b4[t] : 0.0f;
  // stage W1 (16 chunks: 4 waves x 4) and W4 (8 chunks: 4 waves x 2)
#pragma unroll
  for (int c = 0; c < 4; ++c)
    gld16(Wf + W1F + (c * 4 + wv) * 512 + lane * 8, &W1s[(c * 4 + wv) * 512]);
#pragma unroll
  for (int c = 0; c < 2; ++c)
    gld16(Wf + W4F + (c * 4 + wv) * 512 + lane * 8, &W4s[(c * 4 + wv) * 512]);
  __syncthreads();
  const int maxnf = nfS[RPB - 1];   // rows sorted by n_full

  f32x4 acc[16];
  v8s bact[8];
  const f32x4 Z4 = {0.0f, 0.0f, 0.0f, 0.0f};

  // ---- ring pipeline: phase ap (one 16KB k-slice); [layer:1][ks:3] = ap&15.
  // Each wave stages 4 chunks (4 gld16) per slice.
#define ISSUE_SLICE(AP, BUF)                                                  \
  do {                                                                        \
    int sp_ = (AP) & 15;                                                      \
    int off_ = ((sp_ >> 3) ? W3F : W2F) + (sp_ & 7) * 8192;                   \
    u16* dst_ = &ringS[(BUF)][0];                                             \
    _Pragma("unroll") for (int c_ = 0; c_ < 4; ++c_)                          \
      gld16(Wf + off_ + (c_ * 4 + wv) * 512 + lane * 8,                       \
            dst_ + (c_ * 4 + wv) * 512);                                      \
  } while (0)

  int ap = 0;   // next slice to consume
  int bc = 0;   // its ring buffer
  ISSUE_SLICE(0, 0);

#define PACK_BACT()                                              \
  do {                                                           \
    _Pragma("unroll") for (int ks = 0; ks < 8; ++ks) {           \
      f32x4 a0 = silu4(acc[2 * ks]);                             \
      f32x4 a1 = silu4(acc[2 * ks + 1]);                         \
      union { int4 i; v8s s; } u_;                               \
      u_.i.x = (int)pk2(a0[0], a0[1]);                           \
      u_.i.y = (int)pk2(a0[2], a0[3]);                           \
      u_.i.z = (int)pk2(a1[0], a1[1]);                           \
      u_.i.w = (int)pk2(a1[2], a1[3]);                           \
      bact[ks] = u_.s;                                           \
    }                                                            \
  } while (0)

  for (int ev = 0; ev <= maxnf; ++ev) {
    const bool partial = (ev == maxnf);

    // ---- layer-1 B-fragment: hi/lo split + constant-1 slot (f=12, q=3) ----
    v8s b1f;
    {
      const int row = rb + n;
      const float4 st = *(const float4*)&stS[row * 4];
      const float qop = qopS[row];
      const float dzv = partial ? fracS[row] * dzS[row] : dzS[row];
      u32 h01 = pk2(st.x, st.y), h23 = pk2(st.z, st.w), hqd = pk2(qop, dzv);
      float l0 = st.x - bfu(h01, 0), l1 = st.y - bfu(h01, 1);
      float l2 = st.z - bfu(h23, 0), l3 = st.w - bfu(h23, 1);
      float lq = qop - bfu(hqd, 0), ld = dzv - bfu(hqd, 1);
      u32 w0 = 0, w1 = 0;
      if (q == 0) { w0 = h01; w1 = h23; }
      else if (q == 1) { w0 = hqd; w1 = pk2(l0, l1); }
      else if (q == 2) { w0 = pk2(l2, l3); w1 = pk2(lq, ld); }
      else { w0 = 0x00003F80u; }   // f=12 slot = 1.0 -> W1 row 12 = b1
      union { int4 i; v8s s; } u_;
      u_.i.x = (int)w0; u_.i.y = (int)w1; u_.i.z = 0; u_.i.w = 0;
      b1f = u_.s;
    }

    // ---- L1: acc = W1^T @ [x,1] (bias via const-1 feature) ----
#pragma unroll
    for (int mt = 0; mt < 16; ++mt) {
      const v8s w = *(const v8s*)&W1s[mt * 512 + lane * 8];
      acc[mt] = MFMA(w, b1f, Z4);
    }
    PACK_BACT();

    // ---- L2, L3: 256x256; one full k-slice per barrier (16 phases/eval) ----
#pragma unroll
    for (int layer = 0; layer < 2; ++layer) {
      const int Lb = (layer == 0) ? 0 : 256;
#pragma unroll
      for (int mt = 0; mt < 16; ++mt) {
        const float4 bb = *(const float4*)&biasS[Lb + mt * 16 + q * 4];
        const f32x4 binit = {bb.x, bb.y, bb.z, bb.w};
        acc[mt] = binit;
      }
#pragma unroll
      for (int ks = 0; ks < 8; ++ks) {
        int bn = bc + 1; if (bn == 3) bn = 0;
        ISSUE_SLICE(ap + 1, bn);                 // 4 gld16 -> in flight
        asm volatile("s_waitcnt vmcnt(4)" ::: "memory");  // slice-ap loads done
        __builtin_amdgcn_sched_barrier(0);
        __builtin_amdgcn_s_barrier();            // publish; NO vmcnt(0) drain
        __builtin_amdgcn_sched_barrier(0);
        asm volatile("" ::: "memory");
        const u16* buf = &ringS[bc][0];
        __builtin_amdgcn_s_setprio(1);
#pragma unroll
        for (int i = 0; i < 8; ++i) {
          const v8s w = *(const v8s*)&buf[i * 512 + lane * 8];
          acc[i] = MFMA(w, bact[ks], acc[i]);
        }
        __builtin_amdgcn_sched_barrier(0);       // cap w-temp liveness at 8
#pragma unroll
        for (int i = 8; i < 16; ++i) {
          const v8s w = *(const v8s*)&buf[i * 512 + lane * 8];
          acc[i] = MFMA(w, bact[ks], acc[i]);
        }
        __builtin_amdgcn_s_setprio(0);
        bc = bn; ++ap;
      }
      PACK_BACT();
    }

    // ---- L4 + masked state update (stS rows are wave-private) ----
    {
      const float4 bb = *(const float4*)&biasS[512 + q * 4];
      f32x4 a4 = {bb.x, bb.y, bb.z, bb.w};
#pragma unroll
      for (int ks = 0; ks < 8; ++ks) {
        const v8s w = *(const v8s*)&W4s[ks * 512 + lane * 8];
        a4 = MFMA(w, bact[ks], a4);
      }
      if (q == 0) {
        const int row = rb + n;
        const bool act = partial ? (fracS[row] > 1e-6f) : (nfS[row] > ev);
        if (act) {
          float4 cur = *(float4*)&stS[row * 4];
          cur.x += a4[0]; cur.y += a4[1];
          cur.z += a4[2]; cur.w += a4[3];
          *(float4*)&stS[row * 4] = cur;
        }
      }
    }
  }
  __syncthreads();   // drains remaining ring prefetch + stS visibility

  // scattered output write (16B per row, rows permuted)
  {
    const int i = t;   // RPB*4 == THREADS
    out[(size_t)rowG[i >> 2] * 4 + (i & 3)] = stS[i];
  }
}

extern "C" void kernel_launch(void* const* d_in, const int* in_sizes, int n_in,
                              void* d_out, int out_size, void* d_ws, size_t ws_size,
                              hipStream_t stream) {
  const float* sdz = (const float*)d_in[0];
  const float* zfr = (const float*)d_in[1];
  const float* W1 = (const float*)d_in[2];
  const float* b1 = (const float*)d_in[3];
  const float* W2 = (const float*)d_in[4];
  const float* b2 = (const float*)d_in[5];
  const float* W3 = (const float*)d_in[6];
  const float* b3 = (const float*)d_in[7];
  const float* W4 = (const float*)d_in[8];
  const float* b4 = (const float*)d_in[9];

  char* ws = (char*)d_ws;
  u16* Wf = (u16*)ws;
  int* bh = (int*)(ws + BH_OFF);
  int* perm = (int*)(ws + PERM_OFF);

  const int B = in_sizes[1];   // 262144

  prep_weights<<<(TOTW + 255) / 256, 256, 0, stream>>>(W1, b1, W2, W3, W4, Wf);
  hist_blocks<<<NSB, 512, 0, stream>>>(zfr, bh, B);
  scan_offsets<<<1, 512, 0, stream>>>(bh);
  scatter_sorted<<<NSB, 512, 0, stream>>>(zfr, bh, perm, B);
  pinn_main<<<B / RPB, THREADS, 0, stream>>>(sdz, zfr, Wf, perm, b2, b3, b4,
                                             (float*)d_out);
}